// Round 1
// 191.805 us; speedup vs baseline: 1.0368x; 1.0368x over previous
//
#include <hip/hip_runtime.h>
#include <hip/hip_bf16.h>

// Problem constants (reference: N=16384, C=2048, F=512; fp32 in/out).
constexpr int N_ROWS = 16384;
constexpr int C_CLS  = 2048;
constexpr int F_DIM  = 512;

typedef __bf16 bf16x8 __attribute__((ext_vector_type(8)));
typedef float  f32x16 __attribute__((ext_vector_type(16)));

struct alignas(16) B8 { __hip_bfloat162 h[4]; };

// ---------------------------------------------------------------------------
// Prep: fp32 -> bf16 + exact fp32 row sum-of-squares.
// Round 7: one row per WAVE (no LDS, no __syncthreads), 2x float4 loads
// (32 B/lane) + one 16 B store/lane, pure shuffle reduction.
// Blocks [0, 4096) -> 4 x rows each; [4096, 4608) -> 4 means rows each.
// ---------------------------------------------------------------------------
__global__ __launch_bounds__(256) void prep_rows(
    const float* __restrict__ x,
    const float* __restrict__ means,
    B8* __restrict__ xb,
    B8* __restrict__ mb,
    float* __restrict__ xsq,
    float* __restrict__ msq)
{
    const int tid  = threadIdx.x;
    const int wv   = tid >> 6;
    const int lane = tid & 63;
    int row = blockIdx.x * 4 + wv;

    const float* src; B8* dst; float* sq;
    if (row < N_ROWS) { src = x; dst = xb; sq = xsq; }
    else { row -= N_ROWS; src = means; dst = mb; sq = msq; }

    const float4* s4 = (const float4*)(src + (size_t)row * F_DIM);
    const float4 a = s4[lane * 2 + 0];
    const float4 b = s4[lane * 2 + 1];

    B8 pk;
    pk.h[0].x = __float2bfloat16(a.x); pk.h[0].y = __float2bfloat16(a.y);
    pk.h[1].x = __float2bfloat16(a.z); pk.h[1].y = __float2bfloat16(a.w);
    pk.h[2].x = __float2bfloat16(b.x); pk.h[2].y = __float2bfloat16(b.y);
    pk.h[3].x = __float2bfloat16(b.z); pk.h[3].y = __float2bfloat16(b.w);
    dst[(size_t)row * (F_DIM / 8) + lane] = pk;

    float ss = a.x * a.x + a.y * a.y + a.z * a.z + a.w * a.w
             + b.x * b.x + b.y * b.y + b.z * b.z + b.w * b.w;
    #pragma unroll
    for (int off = 32; off > 0; off >>= 1) ss += __shfl_down(ss, off);
    if (lane == 0) sq[row] = ss;
}

// ---------------------------------------------------------------------------
// bf16 MFMA NCM kernel — round 7: 256x256 tile, BK=32, 8 waves (512 thr),
// 3-stage LDS ring (96 KB dynamic) with COUNTED vmcnt (T3+T4):
//   * raw s_barrier + "s_waitcnt vmcnt(4)" drains only tile kt's 4 loads;
//     tile kt+1's 4 loads stay in flight ACROSS the barrier (never vmcnt(0)
//     in the main loop — the m97-structure drain was the ~70% stall).
//   * tile kt+2 issued right after barrier(kt): each load has 2 full compute
//     phases (~2000 cyc) to land vs ~900 cyc HBM latency.
//   * buffer safety: stage (kt+2)%3 was last READ at iteration kt-1; all
//     waves' ds_reads of it completed (lgkmcnt before their MFMAs) before
//     they arrived at barrier(kt). Data-ready: each wave drains ITS OWN
//     tile-kt loads via vmcnt BEFORE the barrier; barrier publishes.
//   * 16 MFMA (32x32x16) per wave per barrier — 2x the round-6 amortization.
//   * LDS chunk swizzle UNCHANGED from round 6 (verified conflict-free):
//     chunk c of row r at slot c^((r>>1)&3); read pos = ((2s+khalf)^rsw)*8.
//   * XCD swizzle: 512 wg; XCD x gets wgids [64x, 64x+64) = 8 bands x all 8
//     class tiles -> A chunk (2 MB) + entire mb (2 MB) resident in one L2.
//   * Fragment layout + epilogue math identical to the harness-verified
//     round-6 kernel (col=lane&31, row=(r&3)+8*(r>>2)+4*khalf).
// ---------------------------------------------------------------------------
__device__ __forceinline__ void async_copy16(const __hip_bfloat16* g,
                                             __hip_bfloat16* l)
{
    __builtin_amdgcn_global_load_lds(
        (const __attribute__((address_space(1))) unsigned int*)g,
        (__attribute__((address_space(3))) unsigned int*)l,
        16, 0, 0);
}

constexpr int BM = 256, BN = 256, BK = 32;
constexpr int NKT     = F_DIM / BK;          // 16 k-tiles
constexpr int STAGE_E = (BM + BN) * BK;      // 16384 bf16 = 32 KB per stage
constexpr int NSTAGE  = 3;
constexpr size_t SMEM_BYTES = (size_t)NSTAGE * STAGE_E * sizeof(__hip_bfloat16); // 96 KB

__global__ __launch_bounds__(512, 2) void ncm_gemm(
    const __hip_bfloat16* __restrict__ xb,   // [N, F] bf16
    const __hip_bfloat16* __restrict__ mb,   // [C, F] bf16
    const float* __restrict__ xsq,           // [N]
    const float* __restrict__ msq,           // [C]
    float* __restrict__ out)                 // [N, C] fp32
{
    extern __shared__ __hip_bfloat16 smem[];   // [NSTAGE][A 256x32 | B 256x32]

    const int tid  = threadIdx.x;
    const int wave = tid >> 6;        // 0..7
    const int lane = tid & 63;
    const int wm   = wave >> 2;       // 0..1  (wave row: 128 rows each)
    const int wn   = wave & 3;        // 0..3  (wave col: 64 cols each)

    // XCD-aware decode (512 wg, 512%8==0 -> simple bijective swizzle).
    const int wgid  = (blockIdx.x & 7) * 64 + (blockIdx.x >> 3);
    const int ctile = wgid & 7;           // 0..7   over C
    const int band  = wgid >> 3;          // 0..63  over N
    const int row0 = band * BM;
    const int col0 = ctile * BN;

    // ---- staging: wave stages rows [wave*32, wave*32+32) of A and of B.
    // One copy instr = 16 rows x 4 chunks of 16 B (lane l -> row l>>2,
    // slot l&3, carrying global chunk (l&3)^((l>>3)&3)
    //   => chunk c of row r lands at slot c^((r>>1)&3)).
    const int srow   = lane >> 2;                       // 0..15
    const int schunk = (lane & 3) ^ ((lane >> 3) & 3);  // swizzled chunk
    const __hip_bfloat16* gA =
        xb + (size_t)(row0 + wave * 32 + srow) * F_DIM + schunk * 8;
    const __hip_bfloat16* gB =
        mb + (size_t)(col0 + wave * 32 + srow) * F_DIM + schunk * 8;

    f32x16 acc[4][2] = {};    // wave owns 128(M) x 64(N): 4x2 32x32 frags

    const int lrow  = lane & 31;   // A row (m) / B col (n) within 32-frag
    const int khalf = lane >> 5;   // which 8-wide half of K=16
    const int rsw   = (lrow >> 1) & 3;        // read-side swizzle key
    const int pos0  = ((0 + khalf) ^ rsw) * 8;   // k-step s=0
    const int pos1  = ((2 + khalf) ^ rsw) * 8;   // k-step s=1

    int aoff[4], boff[2];
    #pragma unroll
    for (int mt = 0; mt < 4; ++mt)
        aoff[mt] = (wm * 128 + mt * 32 + lrow) * BK;
    #pragma unroll
    for (int nt = 0; nt < 2; ++nt)
        boff[nt] = BM * BK + (wn * 64 + nt * 32 + lrow) * BK;

    auto stage = [&](int s, int kt) {
        __hip_bfloat16* ba = smem + s * STAGE_E + (wave * 32) * BK;
        __hip_bfloat16* bb = ba + BM * BK;
        const size_t k0 = (size_t)kt * BK;
        #pragma unroll
        for (int i = 0; i < 2; ++i) {
            async_copy16(gA + (size_t)(i * 16) * F_DIM + k0, ba + i * 16 * BK);
            async_copy16(gB + (size_t)(i * 16) * F_DIM + k0, bb + i * 16 * BK);
        }
    };

    // prologue: tiles 0 and 1 in flight (8 loads/thread outstanding)
    stage(0, 0);
    stage(1, 1);

    int p = 0, pn = 2;   // p: stage of tile kt; pn: stage of tile kt+2
    for (int kt = 0; kt < NKT; ++kt) {
        // Drain ONLY tile kt's 4 loads; keep tile kt+1's 4 in flight.
        if (kt < NKT - 1) asm volatile("s_waitcnt vmcnt(4)" ::: "memory");
        else              asm volatile("s_waitcnt vmcnt(0)" ::: "memory");
        __builtin_amdgcn_s_barrier();
        asm volatile("" ::: "memory");

        if (kt + 2 < NKT) stage(pn, kt + 2);   // issue-early, 2 phases deep

        const __hip_bfloat16* sA = smem + p * STAGE_E;
        #pragma unroll
        for (int s = 0; s < 2; ++s) {          // 2 k-steps of 16 within BK=32
            const int pos = s ? pos1 : pos0;
            bf16x8 af[4], bfr[2];
            #pragma unroll
            for (int mt = 0; mt < 4; ++mt)
                af[mt] = *(const bf16x8*)&sA[aoff[mt] + pos];
            #pragma unroll
            for (int nt = 0; nt < 2; ++nt)
                bfr[nt] = *(const bf16x8*)&sA[boff[nt] + pos];
            #pragma unroll
            for (int mt = 0; mt < 4; ++mt)
                #pragma unroll
                for (int nt = 0; nt < 2; ++nt)
                    acc[mt][nt] = __builtin_amdgcn_mfma_f32_32x32x16_bf16(
                        af[mt], bfr[nt], acc[mt][nt], 0, 0, 0);
        }
        p  = (p  == 2) ? 0 : p  + 1;
        pn = (pn == 2) ? 0 : pn + 1;
    }

    // ---- epilogue: 32x32 C/D layout col=lane&31, row=(r&3)+8*(r>>2)+4*khalf
    // (identical to the harness-verified round-6 epilogue; scalar stores are
    // 2x128B-coalesced per wave -> measured exactly ~131 MB HBM writes)
    #pragma unroll
    for (int mt = 0; mt < 4; ++mt) {
        const int rbase = row0 + wm * 128 + mt * 32 + 4 * khalf;
        float xs[16];
        #pragma unroll
        for (int r = 0; r < 16; ++r)
            xs[r] = xsq[rbase + (r & 3) + 8 * (r >> 2)];
        #pragma unroll
        for (int nt = 0; nt < 2; ++nt) {
            const int col = col0 + wn * 64 + nt * 32 + lrow;
            const float ms = msq[col];
            #pragma unroll
            for (int r = 0; r < 16; ++r) {
                const int row = rbase + (r & 3) + 8 * (r >> 2);
                const float d2 =
                    fmaxf(xs[r] + ms - 2.0f * acc[mt][nt][r], 0.0f);
                out[(size_t)row * C_CLS + col] = -sqrtf(d2);
            }
        }
    }
}

// ---------------------------------------------------------------------------
extern "C" void kernel_launch(void* const* d_in, const int* in_sizes, int n_in,
                              void* d_out, int out_size, void* d_ws,
                              size_t ws_size, hipStream_t stream)
{
    const float* x     = (const float*)d_in[0];   // [N, F]
    const float* means = (const float*)d_in[1];   // [C, F]
    float* out = (float*)d_out;                   // [N, C]

    char* ws = (char*)d_ws;
    __hip_bfloat16* xb = (__hip_bfloat16*)ws;                         // 16 MB
    __hip_bfloat16* mb = (__hip_bfloat16*)(ws + (size_t)N_ROWS * F_DIM * 2);
    float* xsq = (float*)(ws + (size_t)(N_ROWS + C_CLS) * F_DIM * 2);
    float* msq = xsq + N_ROWS;

    // 96 KB dynamic LDS (> 64 KB default cap): raise the limit once.
    static bool attr_done = false;
    if (!attr_done) {
        hipFuncSetAttribute((const void*)ncm_gemm,
                            hipFuncAttributeMaxDynamicSharedMemorySize,
                            (int)SMEM_BYTES);
        attr_done = true;
    }

    prep_rows<<<(N_ROWS + C_CLS) / 4, 256, 0, stream>>>(
        x, means, (B8*)xb, (B8*)mb, xsq, msq);

    ncm_gemm<<<dim3(512), dim3(512), SMEM_BYTES, stream>>>(
        xb, mb, xsq, msq, out);
}